// Round 10
// baseline (100.931 us; speedup 1.0000x reference)
//
#include <hip/hip_runtime.h>

// Problem constants
constexpr int CIN  = 6;
constexpr int C0   = 9;          // 6 + 3 one-hot
constexpr int NPTS = 8192;       // B*NP
constexpr float EPS = 1e-5f;

constexpr int GRID = 256;        // 1 block/CU -> co-resident
constexpr int T    = 256;
constexpr int GZ_ELEMS = 8 * 1024 * 64 * 3;   // 6 MB of zeros (output 0)

typedef float f4 __attribute__((ext_vector_type(4)));

// d_ws float offsets: partial sums [blk][ch] + barrier counters
constexpr size_t PS1 = 0;          // [256][64]
constexpr size_t PQ1 = 16384;
constexpr size_t PS2 = 32768;
constexpr size_t PQ2 = 49152;
constexpr size_t PS3 = 65536;      // [256][128]
constexpr size_t PQ3 = 98304;
constexpr size_t BAR = 131072;     // 3 barriers x 512 uints

// LDS geometry (block-private, persists across grid barriers)
constexpr int YS  = 68;    // stride of yb1/yb2 rows [32 pts][64 ch]  (16B-aligned, bank-spread)
constexpr int YS3 = 132;   // stride of yb3 rows [32 pts][128 ch]
constexpr int YB2 = 0;     // arena offsets (floats)
constexpr int YB1 = 2176;  // 32*68
constexpr int YB3 = 2176;  // overlaps dead yb1 in stage 3 (span 32*132 = 4224)

__global__ void k0_init(unsigned* __restrict__ bar) {
    int t = threadIdx.x;
#pragma unroll
    for (int i = 0; i < 6; ++i) bar[i * 256 + t] = 0u;   // 1536 uints
}

__device__ inline unsigned xcc_id() {
    unsigned x;
    asm volatile("s_getreg_b32 %0, hwreg(HW_REG_XCC_ID)" : "=s"(x));
    return x & 7u;
}

// Grid barrier: distributed per-XCD arrival (32 serialized RMWs, not 256),
// leader sums the 8 counters, single RELEASE per XCD. Cross-block data is
// nt-stored (already at HBM once vmcnt drains) and each region is read only
// after its barrier, never before -> no stale-L2 hazard (entry invalidate
// covers prior-replay lines).
__device__ inline void grid_bar(unsigned* __restrict__ bar, int bi) {
    __syncthreads();
    if (threadIdx.x == 0) {
        unsigned* base    = bar + bi * 512;
        unsigned* master  = base + 256;
        unsigned* present = base + 288;
        unsigned  x       = xcc_id();
        unsigned  e = __hip_atomic_fetch_add(base + x * 32, 1u, __ATOMIC_RELAXED,
                                             __HIP_MEMORY_SCOPE_AGENT);
        long tries = 0;
        if (e == 0) {   // XCD leader
            __hip_atomic_fetch_add(present, 1u, __ATOMIC_RELAXED,
                                   __HIP_MEMORY_SCOPE_AGENT);
            for (;;) {
                unsigned s = 0;
#pragma unroll
                for (int i = 0; i < 8; ++i)
                    s += __hip_atomic_load(base + i * 32, __ATOMIC_RELAXED,
                                           __HIP_MEMORY_SCOPE_AGENT);
                if (s >= (unsigned)GRID) break;
                __builtin_amdgcn_s_sleep(2);
                if (++tries > (1L << 26)) break;
            }
            __hip_atomic_fetch_add(master, 1u, __ATOMIC_RELEASE,
                                   __HIP_MEMORY_SCOPE_AGENT);
        }
        unsigned m; tries = 0;
        while ((m = __hip_atomic_load(master, __ATOMIC_RELAXED,
                                      __HIP_MEMORY_SCOPE_AGENT)) == 0u) {
            __builtin_amdgcn_s_sleep(2);
            if (++tries > (1L << 26)) break;
        }
        unsigned P = __hip_atomic_load(present, __ATOMIC_RELAXED,
                                       __HIP_MEMORY_SCOPE_AGENT);
        tries = 0;
        while (m < P) {
            __builtin_amdgcn_s_sleep(2);
            m = __hip_atomic_load(master, __ATOMIC_RELAXED,
                                  __HIP_MEMORY_SCOPE_AGENT);
            if (++tries > (1L << 26)) break;
        }
    }
    __syncthreads();
}

// fold 64-channel partials ([256 blk][64 ch], coalesced) -> per-channel A,B
__device__ inline void fold64(const float* __restrict__ ps, const float* __restrict__ pq,
                              const float* __restrict__ gamma, const float* __restrict__ beta,
                              float* __restrict__ sAB, float* __restrict__ fq) {
    int t = threadIdx.x;
    {
        int c = t & 63, qtr = t >> 6;
        float s = 0.f, q = 0.f;
        for (int i = qtr * 64; i < qtr * 64 + 64; ++i) {
            s += ps[i * 64 + c];
            q += pq[i * 64 + c];
        }
        fq[qtr * 64 + c] = s;
        fq[256 + qtr * 64 + c] = q;
    }
    __syncthreads();
    if (t < 64) {
        float s = fq[t] + fq[64 + t] + fq[128 + t] + fq[192 + t];
        float q = fq[256 + t] + fq[320 + t] + fq[384 + t] + fq[448 + t];
        float mean = s * (1.f / 8192.f);
        float var  = q * (1.f / 8192.f) - mean * mean;
        float A = gamma[t] * rsqrtf(var + EPS);
        sAB[2 * t]     = A;
        sAB[2 * t + 1] = beta[t] - mean * A;
    }
    __syncthreads();
}

__global__ __launch_bounds__(T)
void k_fused(const float* __restrict__ points,
             const float* __restrict__ onehot,
             const int*   __restrict__ idx,
             const float* __restrict__ w1,
             const float* __restrict__ g1, const float* __restrict__ b1,
             const float* __restrict__ w2,
             const float* __restrict__ g2, const float* __restrict__ b2,
             const float* __restrict__ w3,
             const float* __restrict__ g3, const float* __restrict__ b3,
             float* __restrict__ ws, float* __restrict__ out) {
    __shared__ float wsb[128 * 68];   // weights (w1 576 / w2 64x68 / w3 128x68)
    __shared__ float arena[6400];     // yb2 | yb1/yb3 (point-major, see strides)
    __shared__ float sAB[256];        // BN coeffs
    __shared__ float fq[512];         // fold scratch

    unsigned* bar = (unsigned*)(ws + BAR);
    int t = threadIdx.x, blk = blockIdx.x;
    int bb   = blk >> 5;              // batch of this block's 32 points
    int pofs = (blk & 31) * 32;       // offset within the batch's 1024 points

    // ---------------- stage 1: zero-fill + gather + GEMM1 -> yb1 ----------
    {
        f4 z = {0.f, 0.f, 0.f, 0.f};
        f4* gz = (f4*)out + (size_t)blk * 1536 + t;
#pragma unroll
        for (int i = 0; i < 6; ++i) __builtin_nontemporal_store(z, &gz[i * 256]);

        for (int i = t; i < 576; i += 256) wsb[i] = w1[i];
        __syncthreads();

        int pp = t >> 3, gq = t & 7;
        int n  = idx[bb * 1024 + pofs + pp];
        float f[C0];
#pragma unroll
        for (int c = 0; c < CIN; ++c) f[c] = points[((size_t)bb * CIN + c) * 4096 + n];
#pragma unroll
        for (int c = 0; c < 3; ++c)   f[CIN + c] = onehot[bb * 3 + c];

        float acc1[8];
#pragma unroll
        for (int j = 0; j < 8; ++j) {
            float a = 0.f;
#pragma unroll
            for (int c = 0; c < C0; ++c) a += wsb[(gq * 8 + j) * C0 + c] * f[c];
            acc1[j] = a;
        }
        int row = pp * YS + YB1 + gq * 8;
        f4 v0 = {acc1[0], acc1[1], acc1[2], acc1[3]};
        f4 v1 = {acc1[4], acc1[5], acc1[6], acc1[7]};
        *(f4*)&arena[row]     = v0;
        *(f4*)&arena[row + 4] = v1;
        __syncthreads();
        if (t < 64) {
            float s = 0.f, q = 0.f;
            for (int pp2 = 0; pp2 < 32; ++pp2) {
                float v = arena[pp2 * YS + YB1 + t];
                s += v; q += v * v;
            }
            __builtin_nontemporal_store(s, &ws[PS1 + (size_t)blk * 64 + t]);
            __builtin_nontemporal_store(q, &ws[PQ1 + (size_t)blk * 64 + t]);
        }
    }
    grid_bar(bar, 0);

    // ---------------- stage 2: BN1+ReLU -> GEMM2 -> yb2 --------------------
    {
        fold64(ws + PS1, ws + PQ1, g1, b1, sAB, fq);
        for (int i = t; i < 4096; i += 256) wsb[(i >> 6) * 68 + (i & 63)] = w2[i];
        __syncthreads();

        int og = t >> 3, pg = t & 7;
        float acc[4][2] = {};
        for (int ch = 0; ch < 64; ch += 16) {
            f4 xv[4][4];
#pragma unroll
            for (int pt = 0; pt < 4; ++pt) {
                int row = (pt * 8 + pg) * YS + YB1 + ch;
#pragma unroll
                for (int k4 = 0; k4 < 4; ++k4) {
                    f4 raw = *(const f4*)&arena[row + 4 * k4];
#pragma unroll
                    for (int m = 0; m < 4; ++m) {
                        int c = ch + 4 * k4 + m;
                        raw[m] = fmaxf(raw[m] * sAB[2 * c] + sAB[2 * c + 1], 0.f);
                    }
                    xv[pt][k4] = raw;
                }
            }
#pragma unroll
            for (int oj = 0; oj < 2; ++oj) {
                int wrow = (og * 2 + oj) * 68 + ch;
#pragma unroll
                for (int k4 = 0; k4 < 4; ++k4) {
                    f4 wv = *(const f4*)&wsb[wrow + 4 * k4];
#pragma unroll
                    for (int pt = 0; pt < 4; ++pt)
                        acc[pt][oj] += wv.x * xv[pt][k4].x + wv.y * xv[pt][k4].y
                                     + wv.z * xv[pt][k4].z + wv.w * xv[pt][k4].w;
                }
            }
        }
#pragma unroll
        for (int pt = 0; pt < 4; ++pt) {
            int row = (pt * 8 + pg) * YS + YB2;
            arena[row + og * 2 + 0] = acc[pt][0];
            arena[row + og * 2 + 1] = acc[pt][1];
        }
        __syncthreads();
        if (t < 64) {
            float s = 0.f, q = 0.f;
            for (int pp = 0; pp < 32; ++pp) {
                float v = arena[pp * YS + YB2 + t];
                s += v; q += v * v;
            }
            __builtin_nontemporal_store(s, &ws[PS2 + (size_t)blk * 64 + t]);
            __builtin_nontemporal_store(q, &ws[PQ2 + (size_t)blk * 64 + t]);
        }
    }
    grid_bar(bar, 1);

    // ---------------- stage 3: BN2+ReLU -> GEMM3 -> yb3 --------------------
    {
        fold64(ws + PS2, ws + PQ2, g2, b2, sAB, fq);
        for (int i = t; i < 8192; i += 256) wsb[(i >> 6) * 68 + (i & 63)] = w3[i];
        __syncthreads();

        int og = t >> 3, pg = t & 7;
        float acc[4][4] = {};
        for (int ch = 0; ch < 64; ch += 16) {
            f4 xv[4][4];
#pragma unroll
            for (int pt = 0; pt < 4; ++pt) {
                int row = (pt * 8 + pg) * YS + YB2 + ch;
#pragma unroll
                for (int k4 = 0; k4 < 4; ++k4) {
                    f4 raw = *(const f4*)&arena[row + 4 * k4];
#pragma unroll
                    for (int m = 0; m < 4; ++m) {
                        int c = ch + 4 * k4 + m;
                        raw[m] = fmaxf(raw[m] * sAB[2 * c] + sAB[2 * c + 1], 0.f);
                    }
                    xv[pt][k4] = raw;
                }
            }
#pragma unroll
            for (int oj = 0; oj < 4; ++oj) {
                int wrow = (og * 4 + oj) * 68 + ch;
#pragma unroll
                for (int k4 = 0; k4 < 4; ++k4) {
                    f4 wv = *(const f4*)&wsb[wrow + 4 * k4];
#pragma unroll
                    for (int pt = 0; pt < 4; ++pt)
                        acc[pt][oj] += wv.x * xv[pt][k4].x + wv.y * xv[pt][k4].y
                                     + wv.z * xv[pt][k4].z + wv.w * xv[pt][k4].w;
                }
            }
        }
        __syncthreads();   // all yb2 reads done before yb3 overwrites yb1 region
#pragma unroll
        for (int pt = 0; pt < 4; ++pt) {
            int row = (pt * 8 + pg) * YS3 + YB3;
#pragma unroll
            for (int oj = 0; oj < 4; ++oj)
                arena[row + og * 4 + oj] = acc[pt][oj];
        }
        __syncthreads();
        if (t < 128) {
            float s = 0.f, q = 0.f;
            for (int pp = 0; pp < 32; ++pp) {
                float v = arena[pp * YS3 + YB3 + t];
                s += v; q += v * v;
            }
            __builtin_nontemporal_store(s, &ws[PS3 + (size_t)blk * 128 + t]);
            __builtin_nontemporal_store(q, &ws[PQ3 + (size_t)blk * 128 + t]);
        }
    }
    grid_bar(bar, 2);

    // ---------------- stage 4: fold BN3, write pooled ----------------------
    {
        {
            int c = t & 127, h = t >> 7;
            float s = 0.f, q = 0.f;
            for (int i = h * 128; i < h * 128 + 128; ++i) {
                s += ws[PS3 + (size_t)i * 128 + c];
                q += ws[PQ3 + (size_t)i * 128 + c];
            }
            fq[h * 128 + c] = s;
            fq[256 + h * 128 + c] = q;
        }
        __syncthreads();
        if (t < 128) {
            float s = fq[t] + fq[128 + t];
            float q = fq[256 + t] + fq[384 + t];
            float mean = s * (1.f / 8192.f);
            float var  = q * (1.f / 8192.f) - mean * mean;
            float A = g3[t] * rsqrtf(var + EPS);
            sAB[2 * t]     = A;
            sAB[2 * t + 1] = b3[t] - mean * A;
        }
        __syncthreads();
        if (t < 128) {
            float A = sAB[2 * t], Bb = sAB[2 * t + 1];
            float* dst = out + GZ_ELEMS + ((size_t)bb * 128 + t) * 1024 + pofs;
            for (int q4 = 0; q4 < 8; ++q4) {
                f4 r;
#pragma unroll
                for (int m = 0; m < 4; ++m) {
                    float v = arena[(q4 * 4 + m) * YS3 + YB3 + t];
                    r[m] = fmaxf(v * A + Bb, 0.f);
                }
                __builtin_nontemporal_store(r, (f4*)(dst + q4 * 4));
            }
        }
    }
}

extern "C" void kernel_launch(void* const* d_in, const int* in_sizes, int n_in,
                              void* d_out, int out_size, void* d_ws, size_t ws_size,
                              hipStream_t stream) {
    const float* points = (const float*)d_in[1];
    const float* onehot = (const float*)d_in[2];
    const int*   idx    = (const int*)d_in[3];
    const float* w1 = (const float*)d_in[4];
    const float* g1 = (const float*)d_in[5];
    const float* b1 = (const float*)d_in[6];
    const float* w2 = (const float*)d_in[7];
    const float* g2 = (const float*)d_in[8];
    const float* b2 = (const float*)d_in[9];
    const float* w3 = (const float*)d_in[10];
    const float* g3 = (const float*)d_in[11];
    const float* b3 = (const float*)d_in[12];

    float* ws = (float*)d_ws;
    unsigned* bar = (unsigned*)(ws + BAR);

    k0_init<<<1, 256, 0, stream>>>(bar);
    k_fused<<<GRID, T, 0, stream>>>(points, onehot, idx,
                                    w1, g1, b1, w2, g2, b2, w3, g3, b3,
                                    ws, (float*)d_out);
}

// Round 11
// 37.088 us; speedup vs baseline: 2.7214x; 2.7214x over previous
//
#include <hip/hip_runtime.h>

// Problem constants (from reference setup_inputs)
constexpr int B    = 8;
constexpr int N    = 4096;
constexpr int CIN  = 6;
constexpr int NC   = 3;
constexpr int NP   = 1024;
constexpr int C0   = CIN + NC;   // 9
constexpr int M1   = 64;
constexpr int M2   = 64;
constexpr int M3   = 128;
constexpr int NPTS = B * NP;     // 8192 points total
constexpr int NPB  = NPTS / 256; // 32 point-blocks
constexpr float EPS = 1e-5f;

typedef float f4 __attribute__((ext_vector_type(4)));

// d_out layout: [grouped_xyz zeros: B*NP*64*3] ++ [pooled: B*M3*NP]
constexpr int GZ_ELEMS = B * NP * 64 * 3;      // 1,572,864 floats = 6 MB
constexpr int GZ_F4    = GZ_ELEMS / 4;         // 393,216 float4
constexpr int ZSL      = GZ_F4 / 4;            // 98,304 f4 per kernel slice

// d_ws layout (floats):
constexpr size_t Y1_OFF = 0;
constexpr size_t Y2_OFF = Y1_OFF + (size_t)M1 * NPTS;
constexpr size_t Y3_OFF = Y2_OFF + (size_t)M2 * NPTS;
constexpr size_t PS1_OFF = Y3_OFF + (size_t)M3 * NPTS;   // [M1][NPB] sums
constexpr size_t PQ1_OFF = PS1_OFF + (size_t)M1 * NPB;   // [M1][NPB] sumsq
constexpr size_t PS2_OFF = PQ1_OFF + (size_t)M1 * NPB;
constexpr size_t PQ2_OFF = PS2_OFF + (size_t)M2 * NPB;
constexpr size_t PS3_OFF = PQ2_OFF + (size_t)M2 * NPB;
constexpr size_t PQ3_OFF = PS3_OFF + (size_t)M3 * NPB;

// Grid-stride nontemporal zero-fill of slice `sl` (issued first, overlaps compute)
__device__ inline void zero_slice(f4* __restrict__ gz, int sl, int nthreads) {
    f4 z = {0.f, 0.f, 0.f, 0.f};
    int gid = blockIdx.x * blockDim.x + threadIdx.x;
    for (int i = gid; i < ZSL; i += nthreads)
        __builtin_nontemporal_store(z, &gz[sl * ZSL + i]);
}

// Deterministic per-block partial sums for OC channels -> ps/pq [ch][NPB].
template <int OC>
__device__ inline void emit_partials(const float (&acc)[OC], int o0, int pb,
                                     float* __restrict__ ps, float* __restrict__ pq) {
    float sv[OC], qv[OC];
#pragma unroll
    for (int o = 0; o < OC; ++o) { sv[o] = acc[o]; qv[o] = acc[o] * acc[o]; }
#pragma unroll
    for (int off = 32; off; off >>= 1) {
#pragma unroll
        for (int o = 0; o < OC; ++o) {
            sv[o] += __shfl_down(sv[o], off, 64);
            qv[o] += __shfl_down(qv[o], off, 64);
        }
    }
    __shared__ float rs[OC][4], rq[OC][4];
    int lane = threadIdx.x & 63, w = threadIdx.x >> 6;
    if (lane == 0) {
#pragma unroll
        for (int o = 0; o < OC; ++o) { rs[o][w] = sv[o]; rq[o][w] = qv[o]; }
    }
    __syncthreads();
    if (threadIdx.x < OC) {
        int o = threadIdx.x;
        float s = rs[o][0] + rs[o][1] + rs[o][2] + rs[o][3];
        float q = rq[o][0] + rq[o][1] + rq[o][2] + rq[o][3];
        ps[(o0 + o) * NPB + pb] = s;
        pq[(o0 + o) * NPB + pb] = q;
    }
}

// Consumer prologue: fold [CI][NPB] partials into per-channel A,B in LDS.
template <int CI>
__device__ inline void fold_AB(const float* __restrict__ ps, const float* __restrict__ pq,
                               const float* __restrict__ gamma, const float* __restrict__ beta,
                               float* __restrict__ sAB) {
    int t = threadIdx.x;
    if (t < CI) {
        float s = 0.f, q = 0.f;
#pragma unroll 8
        for (int i = 0; i < NPB; ++i) { s += ps[t * NPB + i]; q += pq[t * NPB + i]; }
        float inv_n = 1.0f / (float)NPTS;
        float mean = s * inv_n;
        float var  = q * inv_n - mean * mean;
        float A = gamma[t] * rsqrtf(var + EPS);
        sAB[2 * t]     = A;
        sAB[2 * t + 1] = beta[t] - mean * A;
    }
}

// ---------------- k1: zeros slice 0 + gather + layer-1 GEMM + partials ----
constexpr int OC1 = 8;
__global__ void k1_gather(const float* __restrict__ points,
                          const float* __restrict__ onehot,
                          const int* __restrict__ idx,
                          const float* __restrict__ w1,
                          float* __restrict__ y1,
                          float* __restrict__ ps1, float* __restrict__ pq1,
                          f4* __restrict__ gz) {
    constexpr int NOB = M1 / OC1;             // 8
    zero_slice(gz, 0, NOB * NPB * 256);
    __shared__ float ws[OC1 * C0];
    int t = threadIdx.x;
    int ob = blockIdx.x % NOB;
    int pb = blockIdx.x / NOB;
    int o0 = ob * OC1;
    if (t < OC1 * C0) ws[t] = w1[o0 * C0 + t];
    __syncthreads();

    int p  = pb * 256 + t;
    int b  = p >> 10;
    int pp = p & (NP - 1);
    int n  = idx[b * NP + pp];

    float f[C0];
#pragma unroll
    for (int c = 0; c < CIN; ++c) f[c] = points[((size_t)b * CIN + c) * N + n];
#pragma unroll
    for (int c = 0; c < NC; ++c)  f[CIN + c] = onehot[b * NC + c];

    float acc[OC1];
#pragma unroll
    for (int o = 0; o < OC1; ++o) {
        float a = 0.f;
#pragma unroll
        for (int c = 0; c < C0; ++c) a += ws[o * C0 + c] * f[c];
        acc[o] = a;
        y1[(size_t)(o0 + o) * NPTS + p] = a;
    }
    emit_partials<OC1>(acc, o0, pb, ps1, pq1);
}

// ---------------- k2/k3: BN(prev)+ReLU + GEMM + partials + zero slice -----
template <int CI, int CO, int OC, int SL>
__global__ void k_mlp(const float* __restrict__ yin,
                      const float* __restrict__ psin, const float* __restrict__ pqin,
                      const float* __restrict__ gamma, const float* __restrict__ beta,
                      const float* __restrict__ w,
                      float* __restrict__ yout,
                      float* __restrict__ psout, float* __restrict__ pqout,
                      f4* __restrict__ gz) {
    constexpr int NOB = CO / OC;
    zero_slice(gz, SL, NOB * NPB * 256);
    __shared__ float ws[OC * CI];
    __shared__ float sAB[2 * CI];
    int t = threadIdx.x;
    int ob = blockIdx.x % NOB;
    int pb = blockIdx.x / NOB;
    int o0 = ob * OC;

    fold_AB<CI>(psin, pqin, gamma, beta, sAB);
    for (int i = t; i < OC * CI; i += 256) ws[i] = w[o0 * CI + i];
    __syncthreads();

    int p = pb * 256 + t;
    float x[CI];
#pragma unroll
    for (int c = 0; c < CI; ++c) {
        float v = yin[(size_t)c * NPTS + p] * sAB[2 * c] + sAB[2 * c + 1];
        x[c] = v > 0.f ? v : 0.f;
    }
    float acc[OC];
#pragma unroll
    for (int o = 0; o < OC; ++o) {
        float a = 0.f;
#pragma unroll
        for (int c = 0; c < CI; ++c) a += ws[o * CI + c] * x[c];
        acc[o] = a;
        yout[(size_t)(o0 + o) * NPTS + p] = a;
    }
    __syncthreads();   // shared reuse in emit_partials
    emit_partials<OC>(acc, o0, pb, psout, pqout);
}

// ---------------- k4: BN3+ReLU, write pooled + zero slice 3 ---------------
__global__ void k_out(const float* __restrict__ y3,
                      const float* __restrict__ ps, const float* __restrict__ pq,
                      const float* __restrict__ gamma, const float* __restrict__ beta,
                      float* __restrict__ out, f4* __restrict__ gz) {
    zero_slice(gz, 3, B * M3 * 256);
    int row = blockIdx.x;          // b*M3 + c
    int c = row & (M3 - 1);
    int b = row >> 7;
    __shared__ float sA, sB;
    int t = threadIdx.x;
    if (t == 0) {
        float s = 0.f, q = 0.f;
#pragma unroll 8
        for (int i = 0; i < NPB; ++i) { s += ps[c * NPB + i]; q += pq[c * NPB + i]; }
        float inv_n = 1.0f / (float)NPTS;
        float mean = s * inv_n;
        float var  = q * inv_n - mean * mean;
        float A = gamma[c] * rsqrtf(var + EPS);
        sA = A;
        sB = beta[c] - mean * A;
    }
    __syncthreads();
    float A = sA, Bb = sB;
    const float4 v = ((const float4*)(y3 + (size_t)c * NPTS + b * NP))[t];
    f4 r;
    r.x = fmaxf(v.x * A + Bb, 0.f);
    r.y = fmaxf(v.y * A + Bb, 0.f);
    r.z = fmaxf(v.z * A + Bb, 0.f);
    r.w = fmaxf(v.w * A + Bb, 0.f);
    __builtin_nontemporal_store(r, (f4*)(out + (size_t)row * NP) + t);
}

extern "C" void kernel_launch(void* const* d_in, const int* in_sizes, int n_in,
                              void* d_out, int out_size, void* d_ws, size_t ws_size,
                              hipStream_t stream) {
    const float* points = (const float*)d_in[1];
    const float* onehot = (const float*)d_in[2];
    const int*   idx    = (const int*)d_in[3];
    const float* w1 = (const float*)d_in[4];
    const float* g1 = (const float*)d_in[5];
    const float* b1 = (const float*)d_in[6];
    const float* w2 = (const float*)d_in[7];
    const float* g2 = (const float*)d_in[8];
    const float* b2 = (const float*)d_in[9];
    const float* w3 = (const float*)d_in[10];
    const float* g3 = (const float*)d_in[11];
    const float* b3 = (const float*)d_in[12];

    float* out = (float*)d_out;
    float* ws  = (float*)d_ws;
    float* y1  = ws + Y1_OFF;
    float* y2  = ws + Y2_OFF;
    float* y3  = ws + Y3_OFF;
    float* ps1 = ws + PS1_OFF;  float* pq1 = ws + PQ1_OFF;
    float* ps2 = ws + PS2_OFF;  float* pq2 = ws + PQ2_OFF;
    float* ps3 = ws + PS3_OFF;  float* pq3 = ws + PQ3_OFF;
    f4* gz = (f4*)d_out;

    const int T = 256;

    // 4-node pipeline; 6 MB zero-fill spread across the nodes (nt stores)
    k1_gather<<<(M1 / OC1) * NPB, T, 0, stream>>>(points, onehot, idx, w1,
                                                  y1, ps1, pq1, gz);
    k_mlp<M1, M2, 8, 1><<<(M2 / 8) * NPB, T, 0, stream>>>(y1, ps1, pq1, g1, b1, w2,
                                                          y2, ps2, pq2, gz);
    k_mlp<M2, M3, 8, 2><<<(M3 / 8) * NPB, T, 0, stream>>>(y2, ps2, pq2, g2, b2, w3,
                                                          y3, ps3, pq3, gz);
    k_out<<<B * M3, T, 0, stream>>>(y3, ps3, pq3, g3, b3, out + GZ_ELEMS, gz);
}